// Round 1
// baseline (135.695 us; speedup 1.0000x reference)
//
#include <hip/hip_runtime.h>
#include <hip/hip_bf16.h>

// Per-edge dot product: out[e] = dot(emb[src[e]], emb[dst[e]]), D_FEAT = 128.
// 32 lanes cooperate per edge; each lane loads one float4 (16 B) of each row,
// computes a 4-element partial dot, then a 5-step shfl_xor butterfly reduces
// across the 32-lane group. Wave64 processes 2 edges.
__global__ void dot_predictor_kernel(const float* __restrict__ emb,
                                     const int* __restrict__ src,
                                     const int* __restrict__ dst,
                                     float* __restrict__ out,
                                     int n_edges) {
    const int tid  = blockIdx.x * blockDim.x + threadIdx.x;
    const int lane = tid & 31;   // position within 32-lane group
    const int edge = tid >> 5;   // one edge per 32 lanes
    if (edge >= n_edges) return;

    const size_t s = (size_t)src[edge];
    const size_t d = (size_t)dst[edge];

    const float4* __restrict__ u = reinterpret_cast<const float4*>(emb + s * 128) + lane;
    const float4* __restrict__ v = reinterpret_cast<const float4*>(emb + d * 128) + lane;

    const float4 a = *u;
    const float4 b = *v;

    float p = a.x * b.x + a.y * b.y + a.z * b.z + a.w * b.w;

    // Butterfly reduce across the 32-lane group (masks <= 16 stay within
    // each half of the wave64, so the two edges per wave don't mix).
    p += __shfl_xor(p, 1);
    p += __shfl_xor(p, 2);
    p += __shfl_xor(p, 4);
    p += __shfl_xor(p, 8);
    p += __shfl_xor(p, 16);

    if (lane == 0) out[edge] = p;
}

extern "C" void kernel_launch(void* const* d_in, const int* in_sizes, int n_in,
                              void* d_out, int out_size, void* d_ws, size_t ws_size,
                              hipStream_t stream) {
    const float* emb = (const float*)d_in[0];
    const int*   src = (const int*)d_in[1];
    const int*   dst = (const int*)d_in[2];
    float*       out = (float*)d_out;

    const int n_edges = in_sizes[1];      // E = 1,000,000

    const int threads = 256;              // 8 edges per block (4 waves x 2)
    const int edges_per_block = threads / 32;
    const int blocks = (n_edges + edges_per_block - 1) / edges_per_block;

    dot_predictor_kernel<<<blocks, threads, 0, stream>>>(emb, src, dst, out, n_edges);
}

// Round 2
// 80.025 us; speedup vs baseline: 1.6957x; 1.6957x over previous
//
#include <hip/hip_runtime.h>
#include <hip/hip_bf16.h>

typedef unsigned short u16;
typedef unsigned short u16x8 __attribute__((ext_vector_type(8)));

// ---- Pass 1: convert f32 embedding table -> bf16 (RNE) into d_ws ----
// Each thread handles 8 floats: two float4 loads (32 B), one 16 B store.
__global__ void convert_f32_to_bf16(const float* __restrict__ in,
                                    u16* __restrict__ out, int n8) {
    int i = blockIdx.x * blockDim.x + threadIdx.x;
    if (i >= n8) return;
    const float4* p = reinterpret_cast<const float4*>(in) + 2 * (size_t)i;
    float4 a = p[0];
    float4 b = p[1];
    float f[8] = {a.x, a.y, a.z, a.w, b.x, b.y, b.z, b.w};
    u16x8 r;
#pragma unroll
    for (int j = 0; j < 8; ++j) {
        unsigned u = __float_as_uint(f[j]);
        // round-to-nearest-even to bf16 (inputs are finite normals; no NaN care)
        u = u + 0x7FFFu + ((u >> 16) & 1u);
        r[j] = (u16)(u >> 16);
    }
    *(reinterpret_cast<u16x8*>(out) + i) = r;
}

// ---- Pass 2: per-edge dot on bf16 rows ----
// 16 lanes per edge; lane j loads bf16[8] (16 B) of each row, partial dot in
// f32, then 4-step shfl_xor reduce within the 16-lane group.
__global__ void gather_dot_bf16(const u16* __restrict__ emb,
                                const int* __restrict__ src,
                                const int* __restrict__ dst,
                                float* __restrict__ out, int n_edges) {
    int tid  = blockIdx.x * blockDim.x + threadIdx.x;
    int lane = tid & 15;
    int edge = tid >> 4;
    if (edge >= n_edges) return;

    size_t s = (size_t)src[edge];
    size_t d = (size_t)dst[edge];

    const u16x8 a = *(reinterpret_cast<const u16x8*>(emb + s * 128) + lane);
    const u16x8 b = *(reinterpret_cast<const u16x8*>(emb + d * 128) + lane);

    float p = 0.f;
#pragma unroll
    for (int j = 0; j < 8; ++j) {
        float af = __uint_as_float(((unsigned)a[j]) << 16);
        float bf = __uint_as_float(((unsigned)b[j]) << 16);
        p = fmaf(af, bf, p);
    }

    // masks <= 8 keep lanes within their 16-lane group inside the wave64
    p += __shfl_xor(p, 1);
    p += __shfl_xor(p, 2);
    p += __shfl_xor(p, 4);
    p += __shfl_xor(p, 8);

    if (lane == 0) out[edge] = p;
}

// ---- Fallback: round-1 f32 kernel (used only if d_ws is too small) ----
__global__ void gather_dot_f32(const float* __restrict__ emb,
                               const int* __restrict__ src,
                               const int* __restrict__ dst,
                               float* __restrict__ out, int n_edges) {
    int tid  = blockIdx.x * blockDim.x + threadIdx.x;
    int lane = tid & 31;
    int edge = tid >> 5;
    if (edge >= n_edges) return;
    size_t s = (size_t)src[edge];
    size_t d = (size_t)dst[edge];
    float4 a = *(reinterpret_cast<const float4*>(emb + s * 128) + lane);
    float4 b = *(reinterpret_cast<const float4*>(emb + d * 128) + lane);
    float p = a.x * b.x + a.y * b.y + a.z * b.z + a.w * b.w;
    p += __shfl_xor(p, 1);
    p += __shfl_xor(p, 2);
    p += __shfl_xor(p, 4);
    p += __shfl_xor(p, 8);
    p += __shfl_xor(p, 16);
    if (lane == 0) out[edge] = p;
}

extern "C" void kernel_launch(void* const* d_in, const int* in_sizes, int n_in,
                              void* d_out, int out_size, void* d_ws, size_t ws_size,
                              hipStream_t stream) {
    const float* emb = (const float*)d_in[0];
    const int*   src = (const int*)d_in[1];
    const int*   dst = (const int*)d_in[2];
    float*       out = (float*)d_out;

    const int n_emb   = in_sizes[0];  // N_NODES * D_FEAT = 12,800,000
    const int n_edges = in_sizes[1];  // 1,000,000

    const size_t bf16_bytes = (size_t)n_emb * sizeof(u16);

    if (ws_size >= bf16_bytes) {
        u16* emb16 = (u16*)d_ws;

        // Pass 1: f32 -> bf16 table
        const int n8 = n_emb / 8;
        convert_f32_to_bf16<<<(n8 + 255) / 256, 256, 0, stream>>>(emb, emb16, n8);

        // Pass 2: gather + dot, 16 lanes/edge
        const int threads = 256;
        const int edges_per_block = threads / 16;
        const int blocks = (n_edges + edges_per_block - 1) / edges_per_block;
        gather_dot_bf16<<<blocks, threads, 0, stream>>>(emb16, src, dst, out, n_edges);
    } else {
        const int threads = 256;
        const int edges_per_block = threads / 32;
        const int blocks = (n_edges + edges_per_block - 1) / edges_per_block;
        gather_dot_f32<<<blocks, threads, 0, stream>>>(emb, src, dst, out, n_edges);
    }
}

// Round 3
// 78.309 us; speedup vs baseline: 1.7328x; 1.0219x over previous
//
#include <hip/hip_runtime.h>
#include <hip/hip_bf16.h>

typedef unsigned short u16;
typedef unsigned short u16x8 __attribute__((ext_vector_type(8)));

// ---- Pass 1: convert f32 embedding table -> bf16 (RNE) into d_ws ----
__global__ void convert_f32_to_bf16(const float* __restrict__ in,
                                    u16* __restrict__ out, int n8) {
    int i = blockIdx.x * blockDim.x + threadIdx.x;
    if (i >= n8) return;
    const float4* p = reinterpret_cast<const float4*>(in) + 2 * (size_t)i;
    float4 a = p[0];
    float4 b = p[1];
    float f[8] = {a.x, a.y, a.z, a.w, b.x, b.y, b.z, b.w};
    u16x8 r;
#pragma unroll
    for (int j = 0; j < 8; ++j) {
        unsigned u = __float_as_uint(f[j]);
        u = u + 0x7FFFu + ((u >> 16) & 1u);  // RNE to bf16
        r[j] = (u16)(u >> 16);
    }
    *(reinterpret_cast<u16x8*>(out) + i) = r;
}

__device__ inline float dot8(const u16x8& a, const u16x8& b) {
    float p = 0.f;
#pragma unroll
    for (int j = 0; j < 8; ++j) {
        float af = __uint_as_float(((unsigned)a[j]) << 16);
        float bf = __uint_as_float(((unsigned)b[j]) << 16);
        p = fmaf(af, bf, p);
    }
    return p;
}

__device__ inline float reduce16(float p) {
    p += __shfl_xor(p, 1);
    p += __shfl_xor(p, 2);
    p += __shfl_xor(p, 4);
    p += __shfl_xor(p, 8);
    return p;
}

// ---- Pass 2: per-edge dot on bf16 rows, 4 edges per 16-lane group ----
// 8 independent 16-B gather loads in flight per thread (4x the MLP of the
// previous version) to discriminate latency-bound vs byte-path-bound.
__global__ void gather_dot_bf16_x4(const u16* __restrict__ emb,
                                   const int* __restrict__ src,
                                   const int* __restrict__ dst,
                                   float* __restrict__ out, int n_edges) {
    int tid  = blockIdx.x * blockDim.x + threadIdx.x;
    int lane = tid & 15;
    int g    = tid >> 4;         // 4 edges per group
    int e0   = g * 4;
    if (e0 >= n_edges) return;

    const u16x8* __restrict__ base = reinterpret_cast<const u16x8*>(emb);

    if (e0 + 3 < n_edges) {
        // vector index loads (uniform within the 16-lane group)
        int4 s4 = *reinterpret_cast<const int4*>(src + e0);
        int4 d4 = *reinterpret_cast<const int4*>(dst + e0);

        // issue all 8 gathers before any use
        u16x8 a0 = base[(size_t)s4.x * 16 + lane];
        u16x8 a1 = base[(size_t)s4.y * 16 + lane];
        u16x8 a2 = base[(size_t)s4.z * 16 + lane];
        u16x8 a3 = base[(size_t)s4.w * 16 + lane];
        u16x8 b0 = base[(size_t)d4.x * 16 + lane];
        u16x8 b1 = base[(size_t)d4.y * 16 + lane];
        u16x8 b2 = base[(size_t)d4.z * 16 + lane];
        u16x8 b3 = base[(size_t)d4.w * 16 + lane];

        float p0 = reduce16(dot8(a0, b0));
        float p1 = reduce16(dot8(a1, b1));
        float p2 = reduce16(dot8(a2, b2));
        float p3 = reduce16(dot8(a3, b3));

        if (lane == 0) {
            float4 r;
            r.x = p0; r.y = p1; r.z = p2; r.w = p3;
            *reinterpret_cast<float4*>(out + e0) = r;
        }
    } else {
        // tail: per-edge scalar path
        for (int e = e0; e < n_edges; ++e) {
            size_t s = (size_t)src[e];
            size_t d = (size_t)dst[e];
            u16x8 a = base[s * 16 + lane];
            u16x8 b = base[d * 16 + lane];
            float p = reduce16(dot8(a, b));
            if (lane == 0) out[e] = p;
        }
    }
}

// ---- Fallback: f32 kernel (used only if d_ws is too small) ----
__global__ void gather_dot_f32(const float* __restrict__ emb,
                               const int* __restrict__ src,
                               const int* __restrict__ dst,
                               float* __restrict__ out, int n_edges) {
    int tid  = blockIdx.x * blockDim.x + threadIdx.x;
    int lane = tid & 31;
    int edge = tid >> 5;
    if (edge >= n_edges) return;
    size_t s = (size_t)src[edge];
    size_t d = (size_t)dst[edge];
    float4 a = *(reinterpret_cast<const float4*>(emb + s * 128) + lane);
    float4 b = *(reinterpret_cast<const float4*>(emb + d * 128) + lane);
    float p = a.x * b.x + a.y * b.y + a.z * b.z + a.w * b.w;
    p += __shfl_xor(p, 1);
    p += __shfl_xor(p, 2);
    p += __shfl_xor(p, 4);
    p += __shfl_xor(p, 8);
    p += __shfl_xor(p, 16);
    if (lane == 0) out[edge] = p;
}

extern "C" void kernel_launch(void* const* d_in, const int* in_sizes, int n_in,
                              void* d_out, int out_size, void* d_ws, size_t ws_size,
                              hipStream_t stream) {
    const float* emb = (const float*)d_in[0];
    const int*   src = (const int*)d_in[1];
    const int*   dst = (const int*)d_in[2];
    float*       out = (float*)d_out;

    const int n_emb   = in_sizes[0];  // 12,800,000
    const int n_edges = in_sizes[1];  // 1,000,000

    const size_t bf16_bytes = (size_t)n_emb * sizeof(u16);

    if (ws_size >= bf16_bytes) {
        u16* emb16 = (u16*)d_ws;

        const int n8 = n_emb / 8;
        convert_f32_to_bf16<<<(n8 + 255) / 256, 256, 0, stream>>>(emb, emb16, n8);

        const int threads = 256;
        const int groups  = (n_edges + 3) / 4;        // 4 edges per 16-lane group
        const int gpb     = threads / 16;             // groups per block
        const int blocks  = (groups + gpb - 1) / gpb;
        gather_dot_bf16_x4<<<blocks, threads, 0, stream>>>(emb16, src, dst, out, n_edges);
    } else {
        const int threads = 256;
        const int edges_per_block = threads / 32;
        const int blocks = (n_edges + edges_per_block - 1) / edges_per_block;
        gather_dot_f32<<<blocks, threads, 0, stream>>>(emb, src, dst, out, n_edges);
    }
}

// Round 4
// 47.768 us; speedup vs baseline: 2.8407x; 1.6393x over previous
//
#include <hip/hip_runtime.h>
#include <hip/hip_bf16.h>

// int8 row-quantized gather-dot.
// Pass 1: quantize each 128-f32 row to int8 with per-row scale (amax/127).
// Pass 2: per-edge dot = scale_u * scale_v * sdot(int8 row_u, int8 row_v).
// Row = 128 B (one/two cache lines) vs bf16's 256 B -> halves demand bytes,
// quarters line touches vs bf16 (4x vs round-2).

#if __has_builtin(__builtin_amdgcn_sdot4)
__device__ inline int dot4i8(int a, int b, int c) {
    return __builtin_amdgcn_sdot4(a, b, c, false);
}
#else
__device__ inline int dot4i8(int a, int b, int c) {
#pragma unroll
    for (int k = 0; k < 4; ++k) {
        int ax = (int)(signed char)((a >> (8 * k)) & 0xFF);
        int bx = (int)(signed char)((b >> (8 * k)) & 0xFF);
        c += ax * bx;
    }
    return c;
}
#endif

__device__ inline unsigned pack4(float x0, float x1, float x2, float x3, float inv) {
    int b0 = __float2int_rn(x0 * inv) & 0xFF;
    int b1 = __float2int_rn(x1 * inv) & 0xFF;
    int b2 = __float2int_rn(x2 * inv) & 0xFF;
    int b3 = __float2int_rn(x3 * inv) & 0xFF;
    return (unsigned)(b0 | (b1 << 8) | (b2 << 16) | (b3 << 24));
}

// ---- Pass 1: f32 rows -> int8 rows + per-row scale ----
// 16 lanes per row. Lane j loads float4 #j and #(j+16) (two fully-coalesced
// 256-B sweeps). Packing order is lane-interleaved but identical for every
// row, and dot is permutation-invariant, so pass 2 stays element-matched.
__global__ void quantize_rows_i8(const float* __restrict__ in,
                                 uint2* __restrict__ q,       // [rows*16]
                                 float* __restrict__ scales,  // [rows]
                                 int n_rows) {
    int tid  = blockIdx.x * blockDim.x + threadIdx.x;
    int lane = tid & 15;
    int row  = tid >> 4;
    if (row >= n_rows) return;

    const float4* p = reinterpret_cast<const float4*>(in + (size_t)row * 128);
    float4 a = p[lane];
    float4 b = p[lane + 16];

    float m = fmaxf(fmaxf(fabsf(a.x), fabsf(a.y)), fmaxf(fabsf(a.z), fabsf(a.w)));
    m = fmaxf(m, fmaxf(fmaxf(fabsf(b.x), fabsf(b.y)), fmaxf(fabsf(b.z), fabsf(b.w))));
    // max across the 16-lane group
    m = fmaxf(m, __shfl_xor(m, 1));
    m = fmaxf(m, __shfl_xor(m, 2));
    m = fmaxf(m, __shfl_xor(m, 4));
    m = fmaxf(m, __shfl_xor(m, 8));

    float inv = (m > 0.f) ? 127.0f / m : 0.f;
    float s   = (m > 0.f) ? m * (1.0f / 127.0f) : 0.f;

    uint2 r;
    r.x = pack4(a.x, a.y, a.z, a.w, inv);
    r.y = pack4(b.x, b.y, b.z, b.w, inv);
    q[(size_t)row * 16 + lane] = r;
    if (lane == 0) scales[row] = s;
}

// ---- Pass 2: per-edge int8 dot ----
// 8 lanes per edge; lane j loads int4 #j (16 int8) of each row.
__global__ void gather_dot_i8(const int4* __restrict__ q,      // rows of 8 int4
                              const float* __restrict__ scales,
                              const int* __restrict__ src,
                              const int* __restrict__ dst,
                              float* __restrict__ out, int n_edges) {
    int tid  = blockIdx.x * blockDim.x + threadIdx.x;
    int lane = tid & 7;
    int e    = tid >> 3;
    if (e >= n_edges) return;

    int s = src[e];
    int d = dst[e];

    int4 a = q[(size_t)s * 8 + lane];
    int4 b = q[(size_t)d * 8 + lane];
    float sc = scales[s] * scales[d];

    int acc = 0;
    acc = dot4i8(a.x, b.x, acc);
    acc = dot4i8(a.y, b.y, acc);
    acc = dot4i8(a.z, b.z, acc);
    acc = dot4i8(a.w, b.w, acc);

    // reduce across the 8-lane group (masks <=4 stay inside the group)
    acc += __shfl_xor(acc, 1);
    acc += __shfl_xor(acc, 2);
    acc += __shfl_xor(acc, 4);

    if (lane == 0) out[e] = (float)acc * sc;
}

// ---- Fallback: direct f32 kernel (if d_ws too small) ----
__global__ void gather_dot_f32(const float* __restrict__ emb,
                               const int* __restrict__ src,
                               const int* __restrict__ dst,
                               float* __restrict__ out, int n_edges) {
    int tid  = blockIdx.x * blockDim.x + threadIdx.x;
    int lane = tid & 31;
    int edge = tid >> 5;
    if (edge >= n_edges) return;
    size_t s = (size_t)src[edge];
    size_t d = (size_t)dst[edge];
    float4 a = *(reinterpret_cast<const float4*>(emb + s * 128) + lane);
    float4 b = *(reinterpret_cast<const float4*>(emb + d * 128) + lane);
    float p = a.x * b.x + a.y * b.y + a.z * b.z + a.w * b.w;
    p += __shfl_xor(p, 1);
    p += __shfl_xor(p, 2);
    p += __shfl_xor(p, 4);
    p += __shfl_xor(p, 8);
    p += __shfl_xor(p, 16);
    if (lane == 0) out[edge] = p;
}

extern "C" void kernel_launch(void* const* d_in, const int* in_sizes, int n_in,
                              void* d_out, int out_size, void* d_ws, size_t ws_size,
                              hipStream_t stream) {
    const float* emb = (const float*)d_in[0];
    const int*   src = (const int*)d_in[1];
    const int*   dst = (const int*)d_in[2];
    float*       out = (float*)d_out;

    const int n_emb   = in_sizes[0];   // 12,800,000
    const int n_edges = in_sizes[1];   // 1,000,000
    const int n_rows  = n_emb / 128;   // 100,000

    const size_t q_bytes  = (size_t)n_rows * 128;            // int8 table
    const size_t sc_bytes = (size_t)n_rows * sizeof(float);  // scales

    if (ws_size >= q_bytes + sc_bytes) {
        uint2* qtab   = (uint2*)d_ws;
        float* scales = (float*)((char*)d_ws + q_bytes);     // 16B-aligned (q_bytes % 16 == 0)

        // Pass 1: quantize (16 lanes/row)
        {
            const int threads = 256;
            const int rows_per_block = threads / 16;
            const int blocks = (n_rows + rows_per_block - 1) / rows_per_block;
            quantize_rows_i8<<<blocks, threads, 0, stream>>>(emb, qtab, scales, n_rows);
        }

        // Pass 2: gather + dot (8 lanes/edge)
        {
            const int threads = 256;
            const int edges_per_block = threads / 8;
            const int blocks = (n_edges + edges_per_block - 1) / edges_per_block;
            gather_dot_i8<<<blocks, threads, 0, stream>>>(
                (const int4*)qtab, scales, src, dst, out, n_edges);
        }
    } else {
        const int threads = 256;
        const int edges_per_block = threads / 32;
        const int blocks = (n_edges + edges_per_block - 1) / edges_per_block;
        gather_dot_f32<<<blocks, threads, 0, stream>>>(emb, src, dst, out, n_edges);
    }
}